// Round 2
// baseline (674.731 us; speedup 1.0000x reference)
//
#include <hip/hip_runtime.h>

// Shapes (fixed by the reference): B=4096, V=64, DI=DO=128
#define BN 4096
#define VN 64
#define DI 128
#define DO 128

typedef __attribute__((ext_vector_type(8))) short short8;
typedef __attribute__((ext_vector_type(4))) float f32x4;

__device__ __forceinline__ float bf2f(unsigned short s) {
    return __uint_as_float(((unsigned)s) << 16);
}
__device__ __forceinline__ unsigned short f2bf(float f) {
    unsigned u = __float_as_uint(f);
    u += 0x7FFF + ((u >> 16) & 1);   // RNE
    return (unsigned short)(u >> 16);
}

// ---------------------------------------------------------------------------
// Kernel -1: dtype detect. bf16 N(0,1) data: ~100% of shorts have exponent
// field in [96,159]. f32 read as shorts: low halves are random mantissa bits
// -> only ~62% "sane". One wave votes; mode 0 = bf16, 1 = f32.
// ---------------------------------------------------------------------------
__global__ void k_detect(const unsigned short* __restrict__ feat,
                         int* __restrict__ mode) {
    int lane = threadIdx.x;   // 64 threads
    int cnt = 0;
#pragma unroll
    for (int j = 0; j < 32; ++j) {
        unsigned short s = feat[lane * 32 + j];
        int e = (s >> 7) & 0xFF;
        cnt += ((e >= 96 && e <= 159) || s == 0) ? 1 : 0;
    }
#pragma unroll
    for (int off = 32; off; off >>= 1) cnt += __shfl_down(cnt, off);
    if (lane == 0) mode[0] = (cnt >= 1946) ? 0 : 1;   // 95% of 2048
}

// ---------------------------------------------------------------------------
// Kernel 0: prep. Blocks 0..63: transpose W[v] (DIxDO) -> Wt[v] (DOxDI) bf16.
// Block 64: adj -> fp32, zero stats (16384 floats).
// ---------------------------------------------------------------------------
__global__ void k_prep(const int* __restrict__ mode,
                       const void* __restrict__ Wraw,
                       const void* __restrict__ adjraw,
                       unsigned short* __restrict__ Wt,
                       float* __restrict__ adjf,
                       float* __restrict__ stats) {
    const int m = mode[0];
    int t = threadIdx.x;
    int blk = blockIdx.x;
    if (blk < VN) {
        unsigned short* Wtv = Wt + (size_t)blk * DI * DO;
        const unsigned short* W16 = (const unsigned short*)Wraw + (size_t)blk * DI * DO;
        const float* Wf = (const float*)Wraw + (size_t)blk * DI * DO;
#pragma unroll
        for (int c = 0; c < 8; ++c) {
            int linear = c * 2048 + t * 8;     // = o*128 + i0
            int o = linear >> 7;
            int i0 = linear & 127;
            short8 sv;
            if (m == 0) {
#pragma unroll
                for (int j = 0; j < 8; ++j) sv[j] = (short)W16[(size_t)(i0 + j) * DO + o];
            } else {
#pragma unroll
                for (int j = 0; j < 8; ++j) sv[j] = (short)f2bf(Wf[(size_t)(i0 + j) * DO + o]);
            }
            *(short8*)(Wtv + linear) = sv;
        }
    } else {
        const unsigned short* a16 = (const unsigned short*)adjraw;
        const float* af = (const float*)adjraw;
#pragma unroll
        for (int k = 0; k < 16; ++k) {
            int i = k * 256 + t;
            adjf[i] = (m == 0) ? bf2f(a16[i]) : af[i];
        }
#pragma unroll
        for (int k = 0; k < 64; ++k) stats[k * 256 + t] = 0.0f;
    }
}

// ---------------------------------------------------------------------------
// Kernel 1: grouped GEMM h[b,v,o] = feat[b,v,:] @ W[v,:,:] + bias[v,:]
// grid (32 b-tiles, 64 v), block 256 (2x2 waves), 128x128 tile.
// Direct-global MFMA fragment loads; BN partial sums via shuffle + atomics.
// ---------------------------------------------------------------------------
__global__ void k_gemm1(const int* __restrict__ mode,
                        const void* __restrict__ featraw,
                        const unsigned short* __restrict__ Wt,
                        const void* __restrict__ biasraw,
                        unsigned short* __restrict__ h,
                        float* __restrict__ sum_, float* __restrict__ sumsq_) {
    const int m = mode[0];
    const int bt = blockIdx.x;
    const int v = blockIdx.y;
    const int tid = threadIdx.x;
    const int w = tid >> 6, lane = tid & 63;
    const int wm = w >> 1, wn = w & 1;
    const int quad = lane >> 4, l16 = lane & 15;

    size_t aidx[4];
    const unsigned short* Bbase[4];
#pragma unroll
    for (int rt = 0; rt < 4; ++rt)
        aidx[rt] = (size_t)(bt * 128 + wm * 64 + rt * 16 + l16) * (VN * DI)
                 + v * DI + quad * 8;
#pragma unroll
    for (int nt = 0; nt < 4; ++nt)
        Bbase[nt] = Wt + (size_t)v * (DI * DO)
                       + (size_t)(wn * 64 + nt * 16 + l16) * DI + quad * 8;

    f32x4 acc[4][4];
#pragma unroll
    for (int rt = 0; rt < 4; ++rt)
#pragma unroll
        for (int nt = 0; nt < 4; ++nt) acc[rt][nt] = (f32x4){0.f, 0.f, 0.f, 0.f};

    if (m == 0) {
        const unsigned short* f16p = (const unsigned short*)featraw;
#pragma unroll
        for (int k0 = 0; k0 < DI; k0 += 32) {
            short8 a[4], bb[4];
#pragma unroll
            for (int rt = 0; rt < 4; ++rt) a[rt] = *(const short8*)(f16p + aidx[rt] + k0);
#pragma unroll
            for (int nt = 0; nt < 4; ++nt) bb[nt] = *(const short8*)(Bbase[nt] + k0);
#pragma unroll
            for (int rt = 0; rt < 4; ++rt)
#pragma unroll
                for (int nt = 0; nt < 4; ++nt)
                    acc[rt][nt] = __builtin_amdgcn_mfma_f32_16x16x32_bf16(
                        a[rt], bb[nt], acc[rt][nt], 0, 0, 0);
        }
    } else {
        const float* ffp = (const float*)featraw;
#pragma unroll
        for (int k0 = 0; k0 < DI; k0 += 32) {
            short8 a[4], bb[4];
#pragma unroll
            for (int rt = 0; rt < 4; ++rt) {
                f32x4 f0 = *(const f32x4*)(ffp + aidx[rt] + k0);
                f32x4 f1 = *(const f32x4*)(ffp + aidx[rt] + k0 + 4);
#pragma unroll
                for (int j = 0; j < 4; ++j) a[rt][j] = (short)f2bf(f0[j]);
#pragma unroll
                for (int j = 0; j < 4; ++j) a[rt][4 + j] = (short)f2bf(f1[j]);
            }
#pragma unroll
            for (int nt = 0; nt < 4; ++nt) bb[nt] = *(const short8*)(Bbase[nt] + k0);
#pragma unroll
            for (int rt = 0; rt < 4; ++rt)
#pragma unroll
                for (int nt = 0; nt < 4; ++nt)
                    acc[rt][nt] = __builtin_amdgcn_mfma_f32_16x16x32_bf16(
                        a[rt], bb[nt], acc[rt][nt], 0, 0, 0);
        }
    }

#pragma unroll
    for (int nt = 0; nt < 4; ++nt) {
        const int col = wn * 64 + nt * 16 + l16;
        const float bv = (m == 0)
            ? bf2f(((const unsigned short*)biasraw)[v * DO + col])
            : ((const float*)biasraw)[v * DO + col];
        float s = 0.f, sq = 0.f;
#pragma unroll
        for (int rt = 0; rt < 4; ++rt)
#pragma unroll
            for (int e = 0; e < 4; ++e) {
                float x = acc[rt][nt][e] + bv;
                acc[rt][nt][e] = x;
                s += x;
                sq += x * x;
            }
        s += __shfl_down(s, 32);  s += __shfl_down(s, 16);
        sq += __shfl_down(sq, 32); sq += __shfl_down(sq, 16);
        if (lane < 16) {
            atomicAdd(&sum_[v * DO + col], s);
            atomicAdd(&sumsq_[v * DO + col], sq);
        }
#pragma unroll
        for (int rt = 0; rt < 4; ++rt)
#pragma unroll
            for (int e = 0; e < 4; ++e) {
                int brow = bt * 128 + wm * 64 + rt * 16 + quad * 4 + e;
                h[(size_t)brow * (VN * DO) + v * DO + col] = f2bf(acc[rt][nt][e]);
            }
    }
}

// ---------------------------------------------------------------------------
// Kernel 2: finalize BN. Blocks 0..63 (u): C0[u,o] = sum_v adj[u,v]*shift[v,o].
// Block 64: scale[v,o] = gamma*rsqrt(var+eps).
// ---------------------------------------------------------------------------
__global__ void k_stats(const int* __restrict__ mode,
                        const float* __restrict__ sum_,
                        const float* __restrict__ sumsq_,
                        const void* __restrict__ adjraw,
                        const void* __restrict__ gammaraw,
                        const void* __restrict__ betaraw,
                        float* __restrict__ scale, float* __restrict__ C0) {
    const int m = mode[0];
    const int o = threadIdx.x;
    const int u = blockIdx.x;
    const float invB = 1.0f / (float)BN;
    if (u < VN) {
        float c0 = 0.f;
#pragma unroll
        for (int v = 0; v < VN; ++v) {
            float mu = sum_[v * DO + o] * invB;
            float var = sumsq_[v * DO + o] * invB - mu * mu;
            float inv = rsqrtf(var + 1e-5f);
            float g = (m == 0) ? bf2f(((const unsigned short*)gammaraw)[v * DO + o])
                               : ((const float*)gammaraw)[v * DO + o];
            float be = (m == 0) ? bf2f(((const unsigned short*)betaraw)[v * DO + o])
                                : ((const float*)betaraw)[v * DO + o];
            float av = (m == 0) ? bf2f(((const unsigned short*)adjraw)[u * VN + v])
                                : ((const float*)adjraw)[u * VN + v];
            float sc = g * inv;
            c0 += av * (be - mu * sc);
        }
        C0[u * DO + o] = c0;
    } else {
#pragma unroll
        for (int v = 0; v < VN; ++v) {
            float mu = sum_[v * DO + o] * invB;
            float var = sumsq_[v * DO + o] * invB - mu * mu;
            float inv = rsqrtf(var + 1e-5f);
            float g = (m == 0) ? bf2f(((const unsigned short*)gammaraw)[v * DO + o])
                               : ((const float*)gammaraw)[v * DO + o];
            scale[v * DO + o] = g * inv;
        }
    }
}

// ---------------------------------------------------------------------------
// Kernel 3: out[b,u,o] = relu( sum_v adj[u,v]*(h[b,v,o]*scale[v,o]) + C0[u,o] )
// One block = 1 batch element (LDS 32 KiB). 256 threads: o = t&127,
// half = t>>7 covers u in [half*32, half*32+32). adjf index wave-uniform.
// ---------------------------------------------------------------------------
__global__ void k_mix(const int* __restrict__ mode,
                      const unsigned short* __restrict__ h,
                      const float* __restrict__ scale,
                      const float* __restrict__ adjf,
                      const float* __restrict__ C0,
                      void* __restrict__ outraw) {
    __shared__ float hs[VN * DO];   // 32 KiB
    const int m = mode[0];
    const int t = threadIdx.x;
    const int b = blockIdx.x;

#pragma unroll
    for (int c = 0; c < 4; ++c) {
        int rem = c * 2048 + t * 8;          // v*128 + o0
        short8 hv = *(const short8*)(h + (size_t)b * (VN * DO) + rem);
#pragma unroll
        for (int j = 0; j < 8; ++j)
            hs[rem + j] = bf2f((unsigned short)hv[j]) * scale[rem + j];
    }
    __syncthreads();

    const int o = t & 127;
    const int half = t >> 7;

#pragma unroll
    for (int ub = 0; ub < 4; ++ub) {
        const int u0 = half * 32 + ub * 8;
        float acc[8];
#pragma unroll
        for (int j = 0; j < 8; ++j) acc[j] = C0[(u0 + j) * DO + o];
#pragma unroll
        for (int vb = 0; vb < 8; ++vb) {
            float hv[8];
#pragma unroll
            for (int k = 0; k < 8; ++k) hv[k] = hs[(vb * 8 + k) * DO + o];
#pragma unroll
            for (int j = 0; j < 8; ++j)
#pragma unroll
                for (int k = 0; k < 8; ++k)
                    acc[j] += adjf[(u0 + j) * VN + vb * 8 + k] * hv[k];
        }
        if (m == 0) {
            unsigned short* out16 = (unsigned short*)outraw;
#pragma unroll
            for (int j = 0; j < 8; ++j)
                out16[(size_t)b * (VN * DO) + (u0 + j) * DO + o] =
                    f2bf(fmaxf(acc[j], 0.0f));
        } else {
            float* outf = (float*)outraw;
#pragma unroll
            for (int j = 0; j < 8; ++j)
                outf[(size_t)b * (VN * DO) + (u0 + j) * DO + o] =
                    fmaxf(acc[j], 0.0f);
        }
    }
}

// ---------------------------------------------------------------------------
extern "C" void kernel_launch(void* const* d_in, const int* in_sizes, int n_in,
                              void* d_out, int out_size, void* d_ws, size_t ws_size,
                              hipStream_t stream) {
    const void* feat  = d_in[0];
    const void* adj   = d_in[1];
    const void* W     = d_in[2];
    const void* bias  = d_in[3];
    const void* gamma = d_in[4];
    const void* beta  = d_in[5];

    char* ws = (char*)d_ws;
    unsigned short* h  = (unsigned short*)ws;                       // 67,108,864 B
    unsigned short* Wt = (unsigned short*)(ws + (size_t)67108864);  //  2,097,152 B
    float* sum_   = (float*)(ws + (size_t)67108864 + 2097152);      // 32 KiB
    float* sumsq_ = sum_ + 8192;                                    // 32 KiB
    float* adjf   = sumsq_ + 8192;                                  // 16 KiB
    float* scale  = adjf + 4096;                                    // 32 KiB
    float* C0     = scale + 8192;                                   // 32 KiB
    int*   mode   = (int*)(C0 + 8192);                              //  4 B

    k_detect<<<dim3(1), dim3(64), 0, stream>>>((const unsigned short*)feat, mode);
    k_prep<<<dim3(65), dim3(256), 0, stream>>>(mode, W, adj, Wt, adjf, sum_);
    k_gemm1<<<dim3(32, 64), dim3(256), 0, stream>>>(mode, feat, Wt, bias, h, sum_, sumsq_);
    k_stats<<<dim3(65), dim3(128), 0, stream>>>(mode, sum_, sumsq_, adj, gamma, beta, scale, C0);
    k_mix<<<dim3(4096), dim3(256), 0, stream>>>(mode, h, scale, adjf, C0, d_out);
}

// Round 3
// 339.777 us; speedup vs baseline: 1.9858x; 1.9858x over previous
//
#include <hip/hip_runtime.h>

// Shapes (fixed by the reference): B=4096, V=64, DI=DO=128. All I/O is f32
// (verified R2: k_mix WRITE_SIZE == 4096*64*128*4 B; detect chose mode=1).
#define BN 4096
#define VN 64
#define DI 128
#define DO 128

typedef __attribute__((ext_vector_type(8))) short short8;
typedef __attribute__((ext_vector_type(4))) float f32x4;

__device__ __forceinline__ float bf2f(unsigned short s) {
    return __uint_as_float(((unsigned)s) << 16);
}
__device__ __forceinline__ unsigned short f2bf(float f) {   // RNE
    unsigned u = __float_as_uint(f);
    u += 0x7FFF + ((u >> 16) & 1);
    return (unsigned short)(u >> 16);
}
// pack bf16(lo)|bf16(hi)<<16 via byte-perm (truncation) — 1 VALU op per 2 elems
__device__ __forceinline__ unsigned pack_bf16_trunc(float lo, float hi) {
    return __builtin_amdgcn_perm(__float_as_uint(hi), __float_as_uint(lo), 0x07060302u);
}

// ---------------------------------------------------------------------------
// Kernel 0: prep.
// Blocks 0..255 (v = blk>>2, q = blk&3): transpose W[v] (DIxDO f32) ->
//   Wt[v] (DOxDI bf16). Reads coalesced along o (lanes = consecutive o).
// Block 256: adj f32 -> adjbf (bf16, row-major [u][v]).
// Block 257: zero sum/sumsq (16384 f32).
// ---------------------------------------------------------------------------
__global__ __launch_bounds__(256) void k_prep(const float* __restrict__ W,
                                              const float* __restrict__ adj,
                                              unsigned short* __restrict__ Wt,
                                              unsigned short* __restrict__ adjbf,
                                              float* __restrict__ stats) {
    const int t = threadIdx.x, blk = blockIdx.x;
    if (blk < 256) {
        const int v = blk >> 2, q = blk & 3;
        const float* Wv = W + (size_t)v * DI * DO;
        unsigned short* Wtv = Wt + (size_t)v * DI * DO;
        const int o = t & 127;
        const int i0 = q * 32 + (t >> 7) * 16;
        short8 s0, s1;
#pragma unroll
        for (int j = 0; j < 8; ++j)
            s0[j] = (short)f2bf(Wv[(size_t)(i0 + j) * DO + o]);
#pragma unroll
        for (int j = 0; j < 8; ++j)
            s1[j] = (short)f2bf(Wv[(size_t)(i0 + 8 + j) * DO + o]);
        *(short8*)(Wtv + o * DI + i0) = s0;
        *(short8*)(Wtv + o * DI + i0 + 8) = s1;
    } else if (blk == 256) {
        short8 s0, s1;
#pragma unroll
        for (int j = 0; j < 8; ++j) s0[j] = (short)f2bf(adj[t * 16 + j]);
#pragma unroll
        for (int j = 0; j < 8; ++j) s1[j] = (short)f2bf(adj[t * 16 + 8 + j]);
        *(short8*)(adjbf + t * 16) = s0;
        *(short8*)(adjbf + t * 16 + 8) = s1;
    } else {
        const f32x4 z = {0.f, 0.f, 0.f, 0.f};
#pragma unroll
        for (int k = 0; k < 16; ++k)
            *(f32x4*)(stats + (size_t)(k * 256 + t) * 4) = z;
    }
}

// ---------------------------------------------------------------------------
// Kernel 1: grouped GEMM h[b,v,o] = feat[b,v,:] @ W[v,:,:] + bias[v,:]
// grid (32 b-tiles, 64 v), block 256 (2x2 waves), 128x128 tile, bf16 MFMA.
// feat read f32 (coalesced full lines per wave), packed to bf16 via v_perm.
// BN partial sums (f32, pre-quantization) via shuffle + atomics. h stored bf16.
// ---------------------------------------------------------------------------
__global__ __launch_bounds__(256) void k_gemm1(const float* __restrict__ feat,
                                               const unsigned short* __restrict__ Wt,
                                               const float* __restrict__ bias,
                                               unsigned short* __restrict__ h,
                                               float* __restrict__ sum_,
                                               float* __restrict__ sumsq_) {
    const int bt = blockIdx.x;
    const int v = blockIdx.y;
    const int tid = threadIdx.x;
    const int w = tid >> 6, lane = tid & 63;
    const int wm = w >> 1, wn = w & 1;
    const int quad = lane >> 4, l16 = lane & 15;

    size_t aidx[4];
    const unsigned short* Bbase[4];
#pragma unroll
    for (int rt = 0; rt < 4; ++rt)
        aidx[rt] = (size_t)(bt * 128 + wm * 64 + rt * 16 + l16) * (VN * DI)
                 + v * DI + quad * 8;
#pragma unroll
    for (int nt = 0; nt < 4; ++nt)
        Bbase[nt] = Wt + (size_t)v * (DI * DO)
                       + (size_t)(wn * 64 + nt * 16 + l16) * DI + quad * 8;

    f32x4 acc[4][4];
#pragma unroll
    for (int rt = 0; rt < 4; ++rt)
#pragma unroll
        for (int nt = 0; nt < 4; ++nt) acc[rt][nt] = (f32x4){0.f, 0.f, 0.f, 0.f};

#pragma unroll
    for (int k0 = 0; k0 < DI; k0 += 32) {
        short8 a[4], bb[4];
#pragma unroll
        for (int rt = 0; rt < 4; ++rt) {
            f32x4 f0 = *(const f32x4*)(feat + aidx[rt] + k0);
            f32x4 f1 = *(const f32x4*)(feat + aidx[rt] + k0 + 4);
            union { short8 s; unsigned u[4]; } pk;
            pk.u[0] = pack_bf16_trunc(f0[0], f0[1]);
            pk.u[1] = pack_bf16_trunc(f0[2], f0[3]);
            pk.u[2] = pack_bf16_trunc(f1[0], f1[1]);
            pk.u[3] = pack_bf16_trunc(f1[2], f1[3]);
            a[rt] = pk.s;
        }
#pragma unroll
        for (int nt = 0; nt < 4; ++nt) bb[nt] = *(const short8*)(Bbase[nt] + k0);
#pragma unroll
        for (int rt = 0; rt < 4; ++rt)
#pragma unroll
            for (int nt = 0; nt < 4; ++nt)
                acc[rt][nt] = __builtin_amdgcn_mfma_f32_16x16x32_bf16(
                    a[rt], bb[nt], acc[rt][nt], 0, 0, 0);
    }

#pragma unroll
    for (int nt = 0; nt < 4; ++nt) {
        const int col = wn * 64 + nt * 16 + l16;
        const float bv = bias[v * DO + col];
        float s = 0.f, sq = 0.f;
#pragma unroll
        for (int rt = 0; rt < 4; ++rt)
#pragma unroll
            for (int e = 0; e < 4; ++e) {
                float x = acc[rt][nt][e] + bv;
                acc[rt][nt][e] = x;
                s += x;
                sq += x * x;
            }
        s += __shfl_down(s, 32);  s += __shfl_down(s, 16);
        sq += __shfl_down(sq, 32); sq += __shfl_down(sq, 16);
        if (lane < 16) {
            atomicAdd(&sum_[v * DO + col], s);
            atomicAdd(&sumsq_[v * DO + col], sq);
        }
#pragma unroll
        for (int rt = 0; rt < 4; ++rt)
#pragma unroll
            for (int e = 0; e < 4; ++e) {
                int brow = bt * 128 + wm * 64 + rt * 16 + quad * 4 + e;
                h[(size_t)brow * (VN * DO) + v * DO + col] = f2bf(acc[rt][nt][e]);
            }
    }
}

// ---------------------------------------------------------------------------
// Kernel 2: finalize BN. Blocks 0..63 (u): C0[u,o] = sum_v adj[u,v]*shift[v,o].
// Block 64: scale[v,o] = gamma*rsqrt(var+eps)  (f32).
// ---------------------------------------------------------------------------
__global__ __launch_bounds__(128) void k_stats(const float* __restrict__ sum_,
                                               const float* __restrict__ sumsq_,
                                               const float* __restrict__ adj,
                                               const float* __restrict__ gamma,
                                               const float* __restrict__ beta,
                                               float* __restrict__ scale,
                                               float* __restrict__ C0) {
    const int o = threadIdx.x;
    const int u = blockIdx.x;
    const float invB = 1.0f / (float)BN;
    if (u < VN) {
        float c0 = 0.f;
#pragma unroll
        for (int v = 0; v < VN; ++v) {
            float mu = sum_[v * DO + o] * invB;
            float var = sumsq_[v * DO + o] * invB - mu * mu;
            float inv = rsqrtf(var + 1e-5f);
            float sc = gamma[v * DO + o] * inv;
            c0 += adj[u * VN + v] * (beta[v * DO + o] - mu * sc);
        }
        C0[u * DO + o] = c0;
    } else {
#pragma unroll
        for (int v = 0; v < VN; ++v) {
            float mu = sum_[v * DO + o] * invB;
            float var = sumsq_[v * DO + o] * invB - mu * mu;
            scale[v * DO + o] = gamma[v * DO + o] * rsqrtf(var + 1e-5f);
        }
    }
}

// ---------------------------------------------------------------------------
// Kernel 3 (MFMA mix): out[b,u,o] = relu( sum_v adj[u,v]*(h[b,v,o]*scale[v,o])
//                                         + C0[u,o] )
// One GEMM M=64(u) K=64(v) per batch elem. Block = 2 batch elems, 4 waves;
// wave (bl = w>>1, nh = w&1) computes M=64 x N=64 (o-half) with 16x16x32 bf16.
// h*scale staged to LDS transposed hsT[o][v] (pad 72: b16 writes 2-way-free,
// b128 frag reads conflict-free, 16B-aligned). adj A-frags resident from
// global bf16 (8 KB, L2-hot).
// ---------------------------------------------------------------------------
__global__ __launch_bounds__(256) void k_mix(const unsigned short* __restrict__ h,
                                             const float* __restrict__ scale,
                                             const unsigned short* __restrict__ adjbf,
                                             const float* __restrict__ C0,
                                             float* __restrict__ out) {
    __shared__ unsigned short hsT[2][DO][72];   // 36,864 B
    const int t = threadIdx.x;
    const int b0 = blockIdx.x * 2;

    // stage: v = lane (bank-spread b16 writes), o-octet per (t>>6, c)
    const int sv = t & 63;
#pragma unroll
    for (int c = 0; c < 8; ++c) {
        const int bl = c >> 2;
        const int o0 = ((t >> 6) << 3) + (c & 3) * 32;
        short8 hv = *(const short8*)(h + ((size_t)(b0 + bl) * VN + sv) * DO + o0);
        f32x4 s0 = *(const f32x4*)(scale + sv * DO + o0);
        f32x4 s1 = *(const f32x4*)(scale + sv * DO + o0 + 4);
#pragma unroll
        for (int j = 0; j < 4; ++j)
            hsT[bl][o0 + j][sv] = f2bf(bf2f((unsigned short)hv[j]) * s0[j]);
#pragma unroll
        for (int j = 0; j < 4; ++j)
            hsT[bl][o0 + 4 + j][sv] = f2bf(bf2f((unsigned short)hv[4 + j]) * s1[j]);
    }
    __syncthreads();

    const int w = t >> 6, lane = t & 63;
    const int bl = w >> 1, nh = w & 1;
    const int quad = lane >> 4, l16 = lane & 15;
    const int b = b0 + bl;

    short8 af[4][2];
#pragma unroll
    for (int mt = 0; mt < 4; ++mt)
#pragma unroll
        for (int ks = 0; ks < 2; ++ks)
            af[mt][ks] = *(const short8*)(adjbf + (mt * 16 + l16) * VN
                                          + ks * 32 + quad * 8);

    f32x4 acc[4][4];
#pragma unroll
    for (int mt = 0; mt < 4; ++mt)
#pragma unroll
        for (int nt = 0; nt < 4; ++nt) acc[mt][nt] = (f32x4){0.f, 0.f, 0.f, 0.f};

#pragma unroll
    for (int nt = 0; nt < 4; ++nt) {
        const unsigned short* bp = &hsT[bl][nh * 64 + nt * 16 + l16][quad * 8];
        short8 bf0 = *(const short8*)(bp);
        short8 bf1 = *(const short8*)(bp + 32);
#pragma unroll
        for (int mt = 0; mt < 4; ++mt) {
            acc[mt][nt] = __builtin_amdgcn_mfma_f32_16x16x32_bf16(
                af[mt][0], bf0, acc[mt][nt], 0, 0, 0);
            acc[mt][nt] = __builtin_amdgcn_mfma_f32_16x16x32_bf16(
                af[mt][1], bf1, acc[mt][nt], 0, 0, 0);
        }
    }

#pragma unroll
    for (int mt = 0; mt < 4; ++mt)
#pragma unroll
        for (int nt = 0; nt < 4; ++nt) {
            const int o = nh * 64 + nt * 16 + l16;
#pragma unroll
            for (int e = 0; e < 4; ++e) {
                const int u = mt * 16 + quad * 4 + e;
                out[((size_t)b * VN + u) * DO + o] =
                    fmaxf(acc[mt][nt][e] + C0[u * DO + o], 0.0f);
            }
        }
}

// ---------------------------------------------------------------------------
extern "C" void kernel_launch(void* const* d_in, const int* in_sizes, int n_in,
                              void* d_out, int out_size, void* d_ws, size_t ws_size,
                              hipStream_t stream) {
    const float* feat  = (const float*)d_in[0];
    const float* adj   = (const float*)d_in[1];
    const float* W     = (const float*)d_in[2];
    const float* bias  = (const float*)d_in[3];
    const float* gamma = (const float*)d_in[4];
    const float* beta  = (const float*)d_in[5];
    float* out = (float*)d_out;

    char* ws = (char*)d_ws;
    unsigned short* h     = (unsigned short*)ws;                        // 67,108,864 B
    unsigned short* Wt    = (unsigned short*)(ws + 67108864ull);        //  2,097,152 B
    unsigned short* adjbf = (unsigned short*)(ws + 69206016ull);        //      8,192 B
    float* sum_   = (float*)(ws + 69214208ull);                         //     32 KiB
    float* sumsq_ = sum_ + 8192;
    float* scale  = sumsq_ + 8192;
    float* C0     = scale + 8192;

    k_prep<<<dim3(258), dim3(256), 0, stream>>>(W, adj, Wt, adjbf, sum_);
    k_gemm1<<<dim3(32, 64), dim3(256), 0, stream>>>(feat, Wt, bias, h, sum_, sumsq_);
    k_stats<<<dim3(65), dim3(128), 0, stream>>>(sum_, sumsq_, adj, gamma, beta, scale, C0);
    k_mix<<<dim3(2048), dim3(256), 0, stream>>>(h, scale, adjbf, C0, out);
}